// Round 20
// baseline (186.905 us; speedup 1.0000x reference)
//
#include <hip/hip_runtime.h>
#include <hip/hip_bf16.h>

// Problem constants
#define B_ 4
#define T_ 2048
#define D_ 1024
#define H_ 16
#define HD_ 64
#define M_ (B_*T_)   // 8192 rows

// Q prescale: 1/sqrt(64) * log2(e)  (softmax done in base-2 domain)
#define QSCALE (0.125f * 1.44269504088896f)

typedef __bf16  bf16x8 __attribute__((ext_vector_type(8)));
typedef __bf16  bf16x4 __attribute__((ext_vector_type(4)));
typedef float   f32x4  __attribute__((ext_vector_type(4)));
typedef ushort  u16x8  __attribute__((ext_vector_type(8)));

__device__ __forceinline__ ushort f2bf(float f) {
  union { float f; uint u; } c; c.f = f;
  uint u = c.u;
  uint r = (u + 0x7FFFu + ((u >> 16) & 1u)) >> 16;  // RNE
  return (ushort)r;
}

__device__ __forceinline__ void gload_lds16(const void* g, void* l) {
  __builtin_amdgcn_global_load_lds(
      (const __attribute__((address_space(1))) void*)g,
      (__attribute__((address_space(3))) void*)l, 16, 0, 0);
}

// ---------------------------------------------------------------- cast x->bf16
__global__ __launch_bounds__(256) void cast_bf16(const float* __restrict__ x,
                                                 ushort* __restrict__ o, int n) {
  int i = (blockIdx.x * 256 + threadIdx.x) * 8;
  if (i >= n) return;
  float4 a = *(const float4*)&x[i];
  float4 b = *(const float4*)&x[i + 4];
  u16x8 r;
  r[0] = f2bf(a.x); r[1] = f2bf(a.y); r[2] = f2bf(a.z); r[3] = f2bf(a.w);
  r[4] = f2bf(b.x); r[5] = f2bf(b.y); r[6] = f2bf(b.z); r[7] = f2bf(b.w);
  *(u16x8*)&o[i] = r;
}

// ------------------------------------------------- transpose W[k][n] -> Wt[n][k] (bf16)
__global__ __launch_bounds__(256) void transw(const float* __restrict__ W0,
                                              const float* __restrict__ W1,
                                              const float* __restrict__ W2,
                                              const float* __restrict__ W3,
                                              ushort* __restrict__ Wt) {
  __shared__ float tile[32][33];
  const float* W = (blockIdx.z == 0) ? W0 : (blockIdx.z == 1) ? W1
                  : (blockIdx.z == 2) ? W2 : W3;
  ushort* dst = Wt + (size_t)blockIdx.z * D_ * D_;
  int tx = threadIdx.x & 31, ty = threadIdx.x >> 5;   // 32 x 8
  int bx = blockIdx.x, by = blockIdx.y;
  #pragma unroll
  for (int i = 0; i < 4; ++i)
    tile[ty + i * 8][tx] = W[(by * 32 + ty + i * 8) * D_ + bx * 32 + tx];
  __syncthreads();
  #pragma unroll
  for (int i = 0; i < 4; ++i)
    dst[(bx * 32 + ty + i * 8) * D_ + by * 32 + tx] = f2bf(tile[tx][ty + i * 8]);
}

// ---------------------------------------------------------------- GEMM  C = A * Bt^T
// Fat-wave single-buffer structure with COMPILE-TIME operand order (r14).
//  SWP=1: mfma(bfv, af) -> r packs 4 consecutive hd/col -> packed bf16x4 /
//         float4+bias.   SWP=0: mfma(af, bfv) -> r packs 4 consecutive t (V).
// NTOFF = n-tile offset of this dispatch (V dispatch covers tiles 16..23).
// XOR bank-swizzle (rule #21) + T1 XCD swizzle.  launch_bounds (256,2):
// (256,3) spills the MI=8 accumulator (r10); runtime SWP branch spills (r13);
// a higher min-waves bound lets the compiler pick a 64-VGPR spill regime (r18).
template<int EPI, int SWP, int NTOFF>
__global__ __launch_bounds__(256, 2) void gemm_bt(const ushort* __restrict__ A,
                                                  const ushort* __restrict__ Bt,
                                                  const float* __restrict__ bias,
                                                  ushort* __restrict__ Qb,
                                                  ushort* __restrict__ Kb,
                                                  ushort* __restrict__ Vt,
                                                  float* __restrict__ Out) {
  constexpr int MI  = (EPI == 0) ? 8 : 4;     // m-frags per wave
  constexpr int BM  = MI * 32;                // 256 / 128
  constexpr int MSP = MI * 16;                // per-wave M span
  __shared__ __align__(16) ushort As[BM * 64];
  __shared__ __align__(16) ushort Bs[128 * 64];
  const int tid = threadIdx.x;
  const int l   = tid & 63;
  const int wid = tid >> 6;              // 0..3
  const int lr  = l & 15, lg = l >> 4;
  const int wm  = wid >> 1, wn = wid & 1;

  // T1: XCD-aware block swizzle (512 / 256 / 512 blocks, all %8==0)
  const int nwgx = gridDim.x;
  int bid = blockIdx.y * nwgx + blockIdx.x;
  int cpx = (nwgx * gridDim.y) >> 3;
  int swz = (bid & 7) * cpx + (bid >> 3);
  const int m0 = (swz / nwgx) * BM;
  const int n0 = (swz % nwgx + NTOFF) * 128;

  const int srow = l >> 3;
  const int sce  = ((l & 7) ^ srow) * 8;       // pre-swizzled source col (elems)
  const int xr   = (lr & 7) << 4;              // read-side byte XOR
  const int ce0  = ((0  + lg * 16) ^ xr) >> 1; // kk=0 col (elems)
  const int ce1  = ((64 + lg * 16) ^ xr) >> 1; // kk=1 col (elems)

  f32x4 acc[MI][4];
  #pragma unroll
  for (int mi = 0; mi < MI; ++mi)
    #pragma unroll
    for (int ni = 0; ni < 4; ++ni)
      acc[mi][ni] = (f32x4){0.f, 0.f, 0.f, 0.f};

  #pragma unroll 1
  for (int k0 = 0; k0 < 1024; k0 += 64) {
    // stage: A = BM/8 chunks total = MI per wave; B = 16 chunks = 4 per wave
    #pragma unroll
    for (int j = 0; j < MI; ++j) {
      int c = wid * MI + j;
      gload_lds16(&A[(size_t)(m0 + c * 8 + srow) * 1024 + k0 + sce],
                  &As[c * 512]);
    }
    #pragma unroll
    for (int j = 0; j < 4; ++j) {
      int c = wid * 4 + j;
      gload_lds16(&Bt[(size_t)(n0 + c * 8 + srow) * 1024 + k0 + sce],
                  &Bs[c * 512]);
    }
    __syncthreads();
    #pragma unroll
    for (int kk = 0; kk < 2; ++kk) {
      const int ce = kk ? ce1 : ce0;
      bf16x8 af[MI], bfv[4];
      #pragma unroll
      for (int mi = 0; mi < MI; ++mi)
        af[mi] = *(const bf16x8*)&As[(wm * MSP + mi * 16 + lr) * 64 + ce];
      #pragma unroll
      for (int ni = 0; ni < 4; ++ni)
        bfv[ni] = *(const bf16x8*)&Bs[(wn * 64 + ni * 16 + lr) * 64 + ce];
      __builtin_amdgcn_s_setprio(1);
      #pragma unroll
      for (int mi = 0; mi < MI; ++mi)
        #pragma unroll
        for (int ni = 0; ni < 4; ++ni) {
          if constexpr (SWP)
            acc[mi][ni] = __builtin_amdgcn_mfma_f32_16x16x32_bf16(
                bfv[ni], af[mi], acc[mi][ni], 0, 0, 0);
          else
            acc[mi][ni] = __builtin_amdgcn_mfma_f32_16x16x32_bf16(
                af[mi], bfv[ni], acc[mi][ni], 0, 0, 0);
        }
      __builtin_amdgcn_s_setprio(0);
    }
    __syncthreads();
  }

  if constexpr (EPI == 0) {
    const int g  = n0 >> 10;                     // 0=Q 1=K 2=V (per dispatch)
    const int hb = ((n0 & 1023) >> 6) + wn;      // head for this wave
    if constexpr (!SWP) {
      // V (unswapped): D row=t -> r packs 4 consecutive t at fixed hd.
      #pragma unroll
      for (int mi = 0; mi < MI; ++mi) {
        int rr0 = m0 + wm * MSP + mi * 16 + lg * 4;
        int b = rr0 >> 11, t = rr0 & 2047;
        #pragma unroll
        for (int ni = 0; ni < 4; ++ni) {
          int hd = ni * 16 + lr;
          bf16x4 p4;
          #pragma unroll
          for (int r = 0; r < 4; ++r) p4[r] = (__bf16)acc[mi][ni][r];
          *(bf16x4*)&Vt[((size_t)(b * H_ + hb) * HD_ + hd) * T_ + t] = p4;
        }
      }
    } else {
      // Q/K (swapped): D col=lr -> t, r packs 4 consecutive hd.
      const float sc = (g == 0) ? QSCALE : 1.0f;
      ushort* dst = (g == 0) ? Qb : Kb;
      #pragma unroll
      for (int mi = 0; mi < MI; ++mi) {
        int rr = m0 + wm * MSP + mi * 16 + lr;
        int b = rr >> 11, t = rr & 2047;
        #pragma unroll
        for (int ni = 0; ni < 4; ++ni) {
          int hd0 = ni * 16 + lg * 4;
          bf16x4 p4;
          #pragma unroll
          for (int r = 0; r < 4; ++r) p4[r] = (__bf16)(acc[mi][ni][r] * sc);
          *(bf16x4*)&dst[((size_t)(b * H_ + hb) * T_ + t) * HD_ + hd0] = p4;
        }
      }
    }
  } else {
    // out-proj (swapped): r packs 4 consecutive cols -> float4 + bias.
    #pragma unroll
    for (int mi = 0; mi < MI; ++mi) {
      int rr = m0 + wm * MSP + mi * 16 + lr;
      #pragma unroll
      for (int ni = 0; ni < 4; ++ni) {
        int cb = n0 + wn * 64 + ni * 16 + lg * 4;
        float4 bv = *(const float4*)&bias[cb];
        float4 f4;
        f4.x = acc[mi][ni][0] + bv.x;
        f4.y = acc[mi][ni][1] + bv.y;
        f4.z = acc[mi][ni][2] + bv.z;
        f4.w = acc[mi][ni][3] + bv.w;
        *(float4*)&Out[(size_t)rr * 1024 + cb] = f4;
      }
    }
  }
}

// ---------------------------------------------------------------- flash attention (causal)
// r20 = r18's V-direct idea with the spill confound removed: launch_bounds
// min-waves back to 3 (r18's min=4 made the compiler target a 64-VGPR regime
// -> accumulator spills, WRITE 16->56 MB -- the actual cause of r18's 2x).
// V is 256 KB/head, L2-resident, shared by 8 blocks on the pinned XCD:
// fragments load DIRECTLY from L2, issued before mask/exp2 so ~200cyc latency
// hides under ~300cyc softmax VALU.  K stays double-buffered in LDS.
// LDS = 16 KB (K dbuf) + 16 KB (P pitch-64 swizzled) = 32 KB -> 4 blocks/CU
// by VGPR (~104).  STATIC-SHIFT base-2 softmax; row-sum via mfma(ap, ones).
__global__ __launch_bounds__(256, 3) void attn_fwd(const ushort* __restrict__ Qb,
                                                   const ushort* __restrict__ Kb,
                                                   const ushort* __restrict__ Vt,
                                                   ushort* __restrict__ Z) {
  __shared__ __align__(16) ushort Ks[2][64 * 64];    // 16 KB (swizzled)
  __shared__ __align__(16) ushort Plds[4][32 * 64];  // per-wave P, 16 KB (swizzled)
  const int tid = threadIdx.x;
  const int l   = tid & 63;
  const int wid = tid >> 6;                // 0..3
  const int lr  = l & 15, lg = l >> 4;
  const int s   = blockIdx.x;
  const int idx = s >> 3;                  // 0..127
  const int bh  = (s & 7) + 8 * (idx & 7); // b*16+h, pinned to XCD s&7
  const int j   = 15 - (idx >> 3);         // q-block 15..0 (longest first)
  const int q0  = j * 128;
  const int qw  = q0 + wid * 32;           // this wave's first q row
  const int NT  = 2 * j + 2;               // kt tiles for this block
  const int myDiag = 2 * j + (wid >> 1);   // wave's last (partial) tile
  const ushort* Qh = Qb + (size_t)bh * T_ * HD_;
  const ushort* Kh = Kb + (size_t)bh * T_ * HD_;
  const ushort* Vh = Vt + (size_t)bh * HD_ * T_;
  ushort* Pl = &Plds[wid][0];

  const int srow = l >> 3;                 // staging: lane's row within chunk
  const int sce  = ((l & 7) ^ srow) * 8;   // pre-swizzled source col (elems)
  const int xrE  = (lr & 7) * 8;           // read-side elem XOR mask
  const int ceK0 = (lg * 8) ^ xrE;
  const int ceK1 = (32 + lg * 8) ^ xrE;

  // Q fragments (B-operand: col=lr -> q row; k = hd)
  const int foff = lr * 64 + lg * 8;
  bf16x8 bq[2][2];
  #pragma unroll
  for (int qi = 0; qi < 2; ++qi)
    #pragma unroll
    for (int kk = 0; kk < 2; ++kk)
      bq[qi][kk] = *(const bf16x8*)&Qh[(qw + qi * 16) * 64 + kk * 32 + foff];

  // ones fragment for MFMA row-sum
  bf16x8 vones;
  #pragma unroll
  for (int jj = 0; jj < 8; ++jj) vones[jj] = (__bf16)1.0f;

  f32x4 o[2][4];
  f32x4 accL[2];
  #pragma unroll
  for (int mi = 0; mi < 2; ++mi) {
    accL[mi] = (f32x4){0.f, 0.f, 0.f, 0.f};
    #pragma unroll
    for (int hi = 0; hi < 4; ++hi)
      o[mi][hi] = (f32x4){0.f, 0.f, 0.f, 0.f};
  }

  // stage K(kt): 8 chunks of 8 rows; wave wid does 2.
#define STAGEK(BUF, KT)                                                         \
  {                                                                             \
    _Pragma("unroll")                                                           \
    for (int c = 0; c < 2; ++c) {                                               \
      int i = wid * 2 + c;                                                      \
      gload_lds16(&Kh[(size_t)((KT) * 64 + i * 8 + srow) * 64 + sce],           \
                  &Ks[BUF][i * 512]);                                           \
    }                                                                           \
  }

  STAGEK(0, 0);
  __syncthreads();

  #pragma unroll 1
  for (int kt = 0; kt < NT; ++kt) {
    const int cur = kt & 1;
    if (kt + 1 < NT) STAGEK(cur ^ 1, kt + 1);

    if (kt <= myDiag) {
      bf16x8 bk[4][2];
      #pragma unroll
      for (int ki = 0; ki < 4; ++ki) {
        bk[ki][0] = *(const bf16x8*)&Ks[cur][(ki * 16 + lr) * 64 + ceK0];
        bk[ki][1] = *(const bf16x8*)&Ks[cur][(ki * 16 + lr) * 64 + ceK1];
      }
      f32x4 st[4][2];
      #pragma unroll
      for (int ki = 0; ki < 4; ++ki)
        #pragma unroll
        for (int qi = 0; qi < 2; ++qi)
          st[ki][qi] = (f32x4){0.f, 0.f, 0.f, 0.f};
      __builtin_amdgcn_s_setprio(1);
      #pragma unroll
      for (int kk = 0; kk < 2; ++kk)
        #pragma unroll
        for (int ki = 0; ki < 4; ++ki)
          #pragma unroll
          for (int qi = 0; qi < 2; ++qi)
            st[ki][qi] = __builtin_amdgcn_mfma_f32_16x16x32_bf16(
                bk[ki][kk], bq[qi][kk], st[ki][qi], 0, 0, 0);
      __builtin_amdgcn_s_setprio(0);

      // ---- V fragments DIRECT from global (L2-resident); issue early so
      // latency hides under the softmax VALU below ----
      bf16x8 bv[4][2];
      #pragma unroll
      for (int hi = 0; hi < 4; ++hi)
        #pragma unroll
        for (int kk = 0; kk < 2; ++kk)
          bv[hi][kk] = *(const bf16x8*)&Vh[(size_t)(hi * 16 + lr) * T_ +
                                           kt * 64 + kk * 32 + lg * 8];

      if (kt == myDiag) {
        const int qbase = qw - kt * 64;
        #pragma unroll
        for (int qi = 0; qi < 2; ++qi) {
          int qoff = qbase + qi * 16 + lr;
          #pragma unroll
          for (int ki = 0; ki < 4; ++ki)
            #pragma unroll
            for (int r = 0; r < 4; ++r)
              if (ki * 16 + lg * 4 + r > qoff) st[ki][qi][r] = -1e30f;
        }
      }

      // P = 2^st -> bf16, packed swizzled LDS store (row sums via MFMA below)
      #pragma unroll
      for (int qi = 0; qi < 2; ++qi)
        #pragma unroll
        for (int ki = 0; ki < 4; ++ki) {
          bf16x4 p4;
          #pragma unroll
          for (int r = 0; r < 4; ++r) p4[r] = (__bf16)exp2f(st[ki][qi][r]);
          *(bf16x4*)&Pl[(qi * 16 + lr) * 64 + ((ki * 16 + lg * 4) ^ xrE)] = p4;
        }

      bf16x8 ap[2][2];
      #pragma unroll
      for (int mi = 0; mi < 2; ++mi)
        #pragma unroll
        for (int kk = 0; kk < 2; ++kk)
          ap[mi][kk] = *(const bf16x8*)&Pl[(mi * 16 + lr) * 64 + ((kk * 32 + lg * 8) ^ xrE)];
      __builtin_amdgcn_s_setprio(1);
      #pragma unroll
      for (int kk = 0; kk < 2; ++kk)
        #pragma unroll
        for (int mi = 0; mi < 2; ++mi) {
          #pragma unroll
          for (int hi = 0; hi < 4; ++hi)
            o[mi][hi] = __builtin_amdgcn_mfma_f32_16x16x32_bf16(
                ap[mi][kk], bv[hi][kk], o[mi][hi], 0, 0, 0);
          accL[mi] = __builtin_amdgcn_mfma_f32_16x16x32_bf16(
              ap[mi][kk], vones, accL[mi], 0, 0, 0);
        }
      __builtin_amdgcn_s_setprio(0);
    }
    __syncthreads();   // drains staging vmcnt; handoff for K buf cur^1
  }
#undef STAGEK

  // ---- normalize + write Z (accL already in O layout: row = lg*4+r) ----
  const int b = bh >> 4, h = bh & 15;
  #pragma unroll
  for (int mi = 0; mi < 2; ++mi)
    #pragma unroll
    for (int r = 0; r < 4; ++r) {
      float rinv = 1.f / accL[mi][r];
      int t = qw + mi * 16 + lg * 4 + r;
      #pragma unroll
      for (int hi = 0; hi < 4; ++hi)
        Z[((size_t)(b * T_ + t)) * D_ + h * 64 + hi * 16 + lr] =
            f2bf(o[mi][hi][r] * rinv);
    }
}

// ---------------------------------------------------------------- launch
extern "C" void kernel_launch(void* const* d_in, const int* in_sizes, int n_in,
                              void* d_out, int out_size, void* d_ws, size_t ws_size,
                              hipStream_t stream) {
  const float* x  = (const float*)d_in[0];
  const float* Wq = (const float*)d_in[1];
  const float* Wk = (const float*)d_in[2];
  const float* Wv = (const float*)d_in[3];
  const float* Wo = (const float*)d_in[4];
  const float* bo = (const float*)d_in[5];
  float* out = (float*)d_out;

  char* ws = (char*)d_ws;
  ushort* xb = (ushort*)(ws);                         // 8192x1024 bf16   (16 MB)
  ushort* Wt = (ushort*)(ws + 16777216);              // 4x1024x1024 bf16 ( 8 MB)
  ushort* Qb = (ushort*)(ws + 25165824);              // [b][h][t][hd]    (16 MB)
  ushort* Kb = (ushort*)(ws + 41943040);              // [b][h][t][hd]    (16 MB)
  ushort* Vt = (ushort*)(ws + 58720256);              // [b][h][hd][t]    (16 MB)
  ushort* Zb = (ushort*)(ws + 75497472);              // [b][t][d]        (16 MB)

  cast_bf16<<<4096, 256, 0, stream>>>(x, xb, M_ * D_);
  transw<<<dim3(32, 32, 4), 256, 0, stream>>>(Wq, Wk, Wv, Wo, Wt);
  // QKV projection: Q/K n-tiles 0..15 (swapped), V n-tiles 16..23 (unswapped)
  gemm_bt<0, 1, 0><<<dim3(16, 32), 256, 0, stream>>>(xb, Wt, nullptr, Qb, Kb, Vt, nullptr);
  gemm_bt<0, 0, 16><<<dim3(8, 32), 256, 0, stream>>>(xb, Wt, nullptr, Qb, Kb, Vt, nullptr);
  attn_fwd<<<1024, 256, 0, stream>>>(Qb, Kb, Vt, Zb);
  gemm_bt<1, 1, 0><<<dim3(8, 64), 256, 0, stream>>>(Zb, Wt + 3 * 1024 * 1024, bo,
                                                    nullptr, nullptr, nullptr, out);
}

// Round 21
// 161.826 us; speedup vs baseline: 1.1550x; 1.1550x over previous
//
#include <hip/hip_runtime.h>
#include <hip/hip_bf16.h>

// Problem constants
#define B_ 4
#define T_ 2048
#define D_ 1024
#define H_ 16
#define HD_ 64
#define M_ (B_*T_)   // 8192 rows

// Q prescale: 1/sqrt(64) * log2(e)  (softmax done in base-2 domain)
#define QSCALE (0.125f * 1.44269504088896f)

typedef __bf16  bf16x8 __attribute__((ext_vector_type(8)));
typedef __bf16  bf16x4 __attribute__((ext_vector_type(4)));
typedef float   f32x4  __attribute__((ext_vector_type(4)));
typedef ushort  u16x8  __attribute__((ext_vector_type(8)));

__device__ __forceinline__ ushort f2bf(float f) {
  union { float f; uint u; } c; c.f = f;
  uint u = c.u;
  uint r = (u + 0x7FFFu + ((u >> 16) & 1u)) >> 16;  // RNE
  return (ushort)r;
}

__device__ __forceinline__ void gload_lds16(const void* g, void* l) {
  __builtin_amdgcn_global_load_lds(
      (const __attribute__((address_space(1))) void*)g,
      (__attribute__((address_space(3))) void*)l, 16, 0, 0);
}

// ---------------------------------------------------------------- cast x->bf16
__global__ __launch_bounds__(256) void cast_bf16(const float* __restrict__ x,
                                                 ushort* __restrict__ o, int n) {
  int i = (blockIdx.x * 256 + threadIdx.x) * 8;
  if (i >= n) return;
  float4 a = *(const float4*)&x[i];
  float4 b = *(const float4*)&x[i + 4];
  u16x8 r;
  r[0] = f2bf(a.x); r[1] = f2bf(a.y); r[2] = f2bf(a.z); r[3] = f2bf(a.w);
  r[4] = f2bf(b.x); r[5] = f2bf(b.y); r[6] = f2bf(b.z); r[7] = f2bf(b.w);
  *(u16x8*)&o[i] = r;
}

// ------------------------------------------------- transpose W[k][n] -> Wt[n][k] (bf16)
__global__ __launch_bounds__(256) void transw(const float* __restrict__ W0,
                                              const float* __restrict__ W1,
                                              const float* __restrict__ W2,
                                              const float* __restrict__ W3,
                                              ushort* __restrict__ Wt) {
  __shared__ float tile[32][33];
  const float* W = (blockIdx.z == 0) ? W0 : (blockIdx.z == 1) ? W1
                  : (blockIdx.z == 2) ? W2 : W3;
  ushort* dst = Wt + (size_t)blockIdx.z * D_ * D_;
  int tx = threadIdx.x & 31, ty = threadIdx.x >> 5;   // 32 x 8
  int bx = blockIdx.x, by = blockIdx.y;
  #pragma unroll
  for (int i = 0; i < 4; ++i)
    tile[ty + i * 8][tx] = W[(by * 32 + ty + i * 8) * D_ + bx * 32 + tx];
  __syncthreads();
  #pragma unroll
  for (int i = 0; i < 4; ++i)
    dst[(bx * 32 + ty + i * 8) * D_ + by * 32 + tx] = f2bf(tile[tx][ty + i * 8]);
}

// ---------------------------------------------------------------- GEMM  C = A * Bt^T
// Fat-wave single-buffer structure with COMPILE-TIME operand order (r14).
//  SWP=1: mfma(bfv, af) -> r packs 4 consecutive hd/col -> packed bf16x4 /
//         float4+bias.   SWP=0: mfma(af, bfv) -> r packs 4 consecutive t (V).
// NTOFF = n-tile offset of this dispatch (V dispatch covers tiles 16..23).
// XOR bank-swizzle (rule #21) + T1 XCD swizzle.  launch_bounds (256,2):
// (256,3) spills the MI=8 accumulator (r10); runtime SWP branch spills (r13);
// a higher min-waves bound lets the compiler pick a 64-VGPR spill regime (r18).
template<int EPI, int SWP, int NTOFF>
__global__ __launch_bounds__(256, 2) void gemm_bt(const ushort* __restrict__ A,
                                                  const ushort* __restrict__ Bt,
                                                  const float* __restrict__ bias,
                                                  ushort* __restrict__ Qb,
                                                  ushort* __restrict__ Kb,
                                                  ushort* __restrict__ Vt,
                                                  float* __restrict__ Out) {
  constexpr int MI  = (EPI == 0) ? 8 : 4;     // m-frags per wave
  constexpr int BM  = MI * 32;                // 256 / 128
  constexpr int MSP = MI * 16;                // per-wave M span
  __shared__ __align__(16) ushort As[BM * 64];
  __shared__ __align__(16) ushort Bs[128 * 64];
  const int tid = threadIdx.x;
  const int l   = tid & 63;
  const int wid = tid >> 6;              // 0..3
  const int lr  = l & 15, lg = l >> 4;
  const int wm  = wid >> 1, wn = wid & 1;

  // T1: XCD-aware block swizzle (512 / 256 / 512 blocks, all %8==0)
  const int nwgx = gridDim.x;
  int bid = blockIdx.y * nwgx + blockIdx.x;
  int cpx = (nwgx * gridDim.y) >> 3;
  int swz = (bid & 7) * cpx + (bid >> 3);
  const int m0 = (swz / nwgx) * BM;
  const int n0 = (swz % nwgx + NTOFF) * 128;

  const int srow = l >> 3;
  const int sce  = ((l & 7) ^ srow) * 8;       // pre-swizzled source col (elems)
  const int xr   = (lr & 7) << 4;              // read-side byte XOR
  const int ce0  = ((0  + lg * 16) ^ xr) >> 1; // kk=0 col (elems)
  const int ce1  = ((64 + lg * 16) ^ xr) >> 1; // kk=1 col (elems)

  f32x4 acc[MI][4];
  #pragma unroll
  for (int mi = 0; mi < MI; ++mi)
    #pragma unroll
    for (int ni = 0; ni < 4; ++ni)
      acc[mi][ni] = (f32x4){0.f, 0.f, 0.f, 0.f};

  #pragma unroll 1
  for (int k0 = 0; k0 < 1024; k0 += 64) {
    // stage: A = BM/8 chunks total = MI per wave; B = 16 chunks = 4 per wave
    #pragma unroll
    for (int j = 0; j < MI; ++j) {
      int c = wid * MI + j;
      gload_lds16(&A[(size_t)(m0 + c * 8 + srow) * 1024 + k0 + sce],
                  &As[c * 512]);
    }
    #pragma unroll
    for (int j = 0; j < 4; ++j) {
      int c = wid * 4 + j;
      gload_lds16(&Bt[(size_t)(n0 + c * 8 + srow) * 1024 + k0 + sce],
                  &Bs[c * 512]);
    }
    __syncthreads();
    #pragma unroll
    for (int kk = 0; kk < 2; ++kk) {
      const int ce = kk ? ce1 : ce0;
      bf16x8 af[MI], bfv[4];
      #pragma unroll
      for (int mi = 0; mi < MI; ++mi)
        af[mi] = *(const bf16x8*)&As[(wm * MSP + mi * 16 + lr) * 64 + ce];
      #pragma unroll
      for (int ni = 0; ni < 4; ++ni)
        bfv[ni] = *(const bf16x8*)&Bs[(wn * 64 + ni * 16 + lr) * 64 + ce];
      __builtin_amdgcn_s_setprio(1);
      #pragma unroll
      for (int mi = 0; mi < MI; ++mi)
        #pragma unroll
        for (int ni = 0; ni < 4; ++ni) {
          if constexpr (SWP)
            acc[mi][ni] = __builtin_amdgcn_mfma_f32_16x16x32_bf16(
                bfv[ni], af[mi], acc[mi][ni], 0, 0, 0);
          else
            acc[mi][ni] = __builtin_amdgcn_mfma_f32_16x16x32_bf16(
                af[mi], bfv[ni], acc[mi][ni], 0, 0, 0);
        }
      __builtin_amdgcn_s_setprio(0);
    }
    __syncthreads();
  }

  if constexpr (EPI == 0) {
    const int g  = n0 >> 10;                     // 0=Q 1=K 2=V (per dispatch)
    const int hb = ((n0 & 1023) >> 6) + wn;      // head for this wave
    if constexpr (!SWP) {
      // V (unswapped): D row=t -> r packs 4 consecutive t at fixed hd.
      #pragma unroll
      for (int mi = 0; mi < MI; ++mi) {
        int rr0 = m0 + wm * MSP + mi * 16 + lg * 4;
        int b = rr0 >> 11, t = rr0 & 2047;
        #pragma unroll
        for (int ni = 0; ni < 4; ++ni) {
          int hd = ni * 16 + lr;
          bf16x4 p4;
          #pragma unroll
          for (int r = 0; r < 4; ++r) p4[r] = (__bf16)acc[mi][ni][r];
          *(bf16x4*)&Vt[((size_t)(b * H_ + hb) * HD_ + hd) * T_ + t] = p4;
        }
      }
    } else {
      // Q/K (swapped): D col=lr -> t, r packs 4 consecutive hd.
      const float sc = (g == 0) ? QSCALE : 1.0f;
      ushort* dst = (g == 0) ? Qb : Kb;
      #pragma unroll
      for (int mi = 0; mi < MI; ++mi) {
        int rr = m0 + wm * MSP + mi * 16 + lr;
        int b = rr >> 11, t = rr & 2047;
        #pragma unroll
        for (int ni = 0; ni < 4; ++ni) {
          int hd0 = ni * 16 + lg * 4;
          bf16x4 p4;
          #pragma unroll
          for (int r = 0; r < 4; ++r) p4[r] = (__bf16)(acc[mi][ni][r] * sc);
          *(bf16x4*)&dst[((size_t)(b * H_ + hb) * T_ + t) * HD_ + hd0] = p4;
        }
      }
    }
  } else {
    // out-proj (swapped): r packs 4 consecutive cols -> float4 + bias.
    #pragma unroll
    for (int mi = 0; mi < MI; ++mi) {
      int rr = m0 + wm * MSP + mi * 16 + lr;
      #pragma unroll
      for (int ni = 0; ni < 4; ++ni) {
        int cb = n0 + wn * 64 + ni * 16 + lg * 4;
        float4 bv = *(const float4*)&bias[cb];
        float4 f4;
        f4.x = acc[mi][ni][0] + bv.x;
        f4.y = acc[mi][ni][1] + bv.y;
        f4.z = acc[mi][ni][2] + bv.z;
        f4.w = acc[mi][ni][3] + bv.w;
        *(float4*)&Out[(size_t)rr * 1024 + cb] = f4;
      }
    }
  }
}

// ---------------------------------------------------------------- flash attention (causal)
// r21 = r17/r19 exactly -- best measured config (162.4 us, reproduced).
// All probed neighbors regressed: single-buffer K/V (r15), 8-wave block (r16),
// V-direct-from-L2 (r18 spill-confounded, r20 clean: per-lane V loads touch
// ~16 cache lines each -> VALUBusy 54->41%), L2-panel map (r11), deep
// counted-vmcnt pipeline (r7).  V-staging via global_load_lds IS the
// coalescing mechanism, not overhead.
// 4 waves/block, 128 q-rows, DOUBLE-buffered K/V in LDS (one barrier per kt),
// pitch-64 XOR-swizzled P.  LDS = 48 KB -> 3 blocks/CU.
// STATIC-SHIFT base-2 softmax; bh pinned to XCD; row-sum via mfma(ap, ones).
__global__ __launch_bounds__(256, 3) void attn_fwd(const ushort* __restrict__ Qb,
                                                   const ushort* __restrict__ Kb,
                                                   const ushort* __restrict__ Vt,
                                                   ushort* __restrict__ Z) {
  __shared__ __align__(16) ushort Ks[2][64 * 64];    // 16 KB (swizzled)
  __shared__ __align__(16) ushort Vs[2][64 * 64];    // 16 KB (swizzled)
  __shared__ __align__(16) ushort Plds[4][32 * 64];  // per-wave P, 16 KB (swizzled)
  const int tid = threadIdx.x;
  const int l   = tid & 63;
  const int wid = tid >> 6;                // 0..3
  const int lr  = l & 15, lg = l >> 4;
  const int s   = blockIdx.x;
  const int idx = s >> 3;                  // 0..127
  const int bh  = (s & 7) + 8 * (idx & 7); // b*16+h, pinned to XCD s&7
  const int j   = 15 - (idx >> 3);         // q-block 15..0 (longest first)
  const int q0  = j * 128;
  const int qw  = q0 + wid * 32;           // this wave's first q row
  const int NT  = 2 * j + 2;               // kt tiles for this block
  const int myDiag = 2 * j + (wid >> 1);   // wave's last (partial) tile
  const ushort* Qh = Qb + (size_t)bh * T_ * HD_;
  const ushort* Kh = Kb + (size_t)bh * T_ * HD_;
  const ushort* Vh = Vt + (size_t)bh * HD_ * T_;
  ushort* Pl = &Plds[wid][0];

  const int srow = l >> 3;                 // staging: lane's row within chunk
  const int sce  = ((l & 7) ^ srow) * 8;   // pre-swizzled source col (elems)
  const int xrE  = (lr & 7) * 8;           // read-side elem XOR mask
  const int ceK0 = (lg * 8) ^ xrE;
  const int ceK1 = (32 + lg * 8) ^ xrE;

  // Q fragments (B-operand: col=lr -> q row; k = hd)
  const int foff = lr * 64 + lg * 8;
  bf16x8 bq[2][2];
  #pragma unroll
  for (int qi = 0; qi < 2; ++qi)
    #pragma unroll
    for (int kk = 0; kk < 2; ++kk)
      bq[qi][kk] = *(const bf16x8*)&Qh[(qw + qi * 16) * 64 + kk * 32 + foff];

  // ones fragment for MFMA row-sum
  bf16x8 vones;
  #pragma unroll
  for (int jj = 0; jj < 8; ++jj) vones[jj] = (__bf16)1.0f;

  f32x4 o[2][4];
  f32x4 accL[2];
  #pragma unroll
  for (int mi = 0; mi < 2; ++mi) {
    accL[mi] = (f32x4){0.f, 0.f, 0.f, 0.f};
    #pragma unroll
    for (int hi = 0; hi < 4; ++hi)
      o[mi][hi] = (f32x4){0.f, 0.f, 0.f, 0.f};
  }

#define STAGEKV(BUF, KT)                                                        \
  {                                                                             \
    _Pragma("unroll")                                                           \
    for (int c = 0; c < 2; ++c) {                                               \
      int i = wid * 2 + c;                                                      \
      gload_lds16(&Kh[(size_t)((KT) * 64 + i * 8 + srow) * 64 + sce],           \
                  &Ks[BUF][i * 512]);                                           \
      gload_lds16(&Vh[(size_t)(i * 8 + srow) * T_ + (KT) * 64 + sce],           \
                  &Vs[BUF][i * 512]);                                           \
    }                                                                           \
  }

  STAGEKV(0, 0);
  __syncthreads();

  #pragma unroll 1
  for (int kt = 0; kt < NT; ++kt) {
    const int cur = kt & 1;
    if (kt + 1 < NT) STAGEKV(cur ^ 1, kt + 1);

    if (kt <= myDiag) {
      bf16x8 bk[4][2];
      #pragma unroll
      for (int ki = 0; ki < 4; ++ki) {
        bk[ki][0] = *(const bf16x8*)&Ks[cur][(ki * 16 + lr) * 64 + ceK0];
        bk[ki][1] = *(const bf16x8*)&Ks[cur][(ki * 16 + lr) * 64 + ceK1];
      }
      f32x4 st[4][2];
      #pragma unroll
      for (int ki = 0; ki < 4; ++ki)
        #pragma unroll
        for (int qi = 0; qi < 2; ++qi)
          st[ki][qi] = (f32x4){0.f, 0.f, 0.f, 0.f};
      __builtin_amdgcn_s_setprio(1);
      #pragma unroll
      for (int kk = 0; kk < 2; ++kk)
        #pragma unroll
        for (int ki = 0; ki < 4; ++ki)
          #pragma unroll
          for (int qi = 0; qi < 2; ++qi)
            st[ki][qi] = __builtin_amdgcn_mfma_f32_16x16x32_bf16(
                bk[ki][kk], bq[qi][kk], st[ki][qi], 0, 0, 0);
      __builtin_amdgcn_s_setprio(0);

      if (kt == myDiag) {
        const int qbase = qw - kt * 64;
        #pragma unroll
        for (int qi = 0; qi < 2; ++qi) {
          int qoff = qbase + qi * 16 + lr;
          #pragma unroll
          for (int ki = 0; ki < 4; ++ki)
            #pragma unroll
            for (int r = 0; r < 4; ++r)
              if (ki * 16 + lg * 4 + r > qoff) st[ki][qi][r] = -1e30f;
        }
      }

      // P = 2^st -> bf16, packed swizzled LDS store (row sums via MFMA below)
      #pragma unroll
      for (int qi = 0; qi < 2; ++qi)
        #pragma unroll
        for (int ki = 0; ki < 4; ++ki) {
          bf16x4 p4;
          #pragma unroll
          for (int r = 0; r < 4; ++r) p4[r] = (__bf16)exp2f(st[ki][qi][r]);
          *(bf16x4*)&Pl[(qi * 16 + lr) * 64 + ((ki * 16 + lg * 4) ^ xrE)] = p4;
        }

      bf16x8 bv[4][2];
      #pragma unroll
      for (int hi = 0; hi < 4; ++hi) {
        bv[hi][0] = *(const bf16x8*)&Vs[cur][(hi * 16 + lr) * 64 + ceK0];
        bv[hi][1] = *(const bf16x8*)&Vs[cur][(hi * 16 + lr) * 64 + ceK1];
      }
      bf16x8 ap[2][2];
      #pragma unroll
      for (int mi = 0; mi < 2; ++mi)
        #pragma unroll
        for (int kk = 0; kk < 2; ++kk)
          ap[mi][kk] = *(const bf16x8*)&Pl[(mi * 16 + lr) * 64 + ((kk * 32 + lg * 8) ^ xrE)];
      __builtin_amdgcn_s_setprio(1);
      #pragma unroll
      for (int kk = 0; kk < 2; ++kk)
        #pragma unroll
        for (int mi = 0; mi < 2; ++mi) {
          #pragma unroll
          for (int hi = 0; hi < 4; ++hi)
            o[mi][hi] = __builtin_amdgcn_mfma_f32_16x16x32_bf16(
                ap[mi][kk], bv[hi][kk], o[mi][hi], 0, 0, 0);
          accL[mi] = __builtin_amdgcn_mfma_f32_16x16x32_bf16(
              ap[mi][kk], vones, accL[mi], 0, 0, 0);
        }
      __builtin_amdgcn_s_setprio(0);
    }
    __syncthreads();   // drains staging vmcnt; handoff for buf cur^1
  }
#undef STAGEKV

  // ---- normalize + write Z (accL already in O layout: row = lg*4+r) ----
  const int b = bh >> 4, h = bh & 15;
  #pragma unroll
  for (int mi = 0; mi < 2; ++mi)
    #pragma unroll
    for (int r = 0; r < 4; ++r) {
      float rinv = 1.f / accL[mi][r];
      int t = qw + mi * 16 + lg * 4 + r;
      #pragma unroll
      for (int hi = 0; hi < 4; ++hi)
        Z[((size_t)(b * T_ + t)) * D_ + h * 64 + hi * 16 + lr] =
            f2bf(o[mi][hi][r] * rinv);
    }
}

// ---------------------------------------------------------------- launch
extern "C" void kernel_launch(void* const* d_in, const int* in_sizes, int n_in,
                              void* d_out, int out_size, void* d_ws, size_t ws_size,
                              hipStream_t stream) {
  const float* x  = (const float*)d_in[0];
  const float* Wq = (const float*)d_in[1];
  const float* Wk = (const float*)d_in[2];
  const float* Wv = (const float*)d_in[3];
  const float* Wo = (const float*)d_in[4];
  const float* bo = (const float*)d_in[5];
  float* out = (float*)d_out;

  char* ws = (char*)d_ws;
  ushort* xb = (ushort*)(ws);                         // 8192x1024 bf16   (16 MB)
  ushort* Wt = (ushort*)(ws + 16777216);              // 4x1024x1024 bf16 ( 8 MB)
  ushort* Qb = (ushort*)(ws + 25165824);              // [b][h][t][hd]    (16 MB)
  ushort* Kb = (ushort*)(ws + 41943040);              // [b][h][t][hd]    (16 MB)
  ushort* Vt = (ushort*)(ws + 58720256);              // [b][h][hd][t]    (16 MB)
  ushort* Zb = (ushort*)(ws + 75497472);              // [b][t][d]        (16 MB)

  cast_bf16<<<4096, 256, 0, stream>>>(x, xb, M_ * D_);
  transw<<<dim3(32, 32, 4), 256, 0, stream>>>(Wq, Wk, Wv, Wo, Wt);
  // QKV projection: Q/K n-tiles 0..15 (swapped), V n-tiles 16..23 (unswapped)
  gemm_bt<0, 1, 0><<<dim3(16, 32), 256, 0, stream>>>(xb, Wt, nullptr, Qb, Kb, Vt, nullptr);
  gemm_bt<0, 0, 16><<<dim3(8, 32), 256, 0, stream>>>(xb, Wt, nullptr, Qb, Kb, Vt, nullptr);
  attn_fwd<<<1024, 256, 0, stream>>>(Qb, Kb, Vt, Zb);
  gemm_bt<1, 1, 0><<<dim3(8, 64), 256, 0, stream>>>(Zb, Wt + 3 * 1024 * 1024, bo,
                                                    nullptr, nullptr, nullptr, out);
}